// Round 6
// baseline (28.221 us; speedup 1.0000x reference)
//
#include <hip/hip_runtime.h>

#define IMG_H 1024
#define IMG_W 1024

#define CC  (-0.1803368801111244f)     // -(1/8)*log2(e)
#define WS1 (-2.8853900817779270e-4f)  // log2(exp(-1/5000))
#define WS2 (-5.7707801635558540e-4f)  // log2(exp(-2/5000))

__device__ __forceinline__ float edgew(float u, float v, float ws) {
    float d = u - v;
    return __builtin_amdgcn_exp2f(fmaf(d * d, CC, ws));
}

__global__ __launch_bounds__(256) void EdgePreserve_kernel(const float* __restrict__ x,
                                                           float* __restrict__ out) {
    const int t   = threadIdx.x;
    const int bid = blockIdx.x;            // ((b*64 + pr)<<1) | ch
    const int ch  = bid & 1;
    const int pr  = (bid >> 1) & 63;
    const int b   = bid >> 7;
    const int r0  = pr << 4;
    const int c0  = (ch << 9) + (t << 1);  // 2 consecutive cols per thread

    const float* base = x + (size_t)b * (IMG_H * IMG_W);
    const int cl = (c0 == 0) ? 1 : c0 - 1;                 // reflect left halo
    const int cr = (c0 + 2 >= IMG_W) ? IMG_W - 2 : c0 + 2; // reflect right halo

    // rows as named scalars: a=r-1, b=r, k=r+1, p=prefetch(r+3); cols {halo, c, c+1, halo}
    float a0,a1,a2,a3, b0,b1,b2,b3, k0,k1,k2,k3, p0,p1,p2,p3;

#define LOADROW(q, d0,d1,d2,d3) { \
    int _r = r0 + (q); \
    int _rr = (_r < 0) ? -_r : ((_r >= IMG_H) ? (2*IMG_H-2-_r) : _r); \
    const float* _rp = base + _rr * IMG_W; \
    float2 _v = *reinterpret_cast<const float2*>(_rp + c0); \
    d0 = _rp[cl]; d1 = _v.x; d2 = _v.y; d3 = _rp[cr]; }

    LOADROW(-1, a0,a1,a2,a3)
    LOADROW( 0, b0,b1,b2,b3)
    LOADROW( 1, k0,k1,k2,k3)
    LOADROW( 2, p0,p1,p2,p3)

    // carried A-B edge weights (from previous iteration's B-K edges):
    // pV_c = w(a_c,b_c); pDL_c = w(a_c,b_{c-1}); pDR_c = w(a_c,b_{c+1})
    float pV1  = edgew(a1,b1,WS1), pV2  = edgew(a2,b2,WS1);
    float pDL2 = edgew(a2,b1,WS2), pDL3 = edgew(a3,b2,WS2);
    float pDR0 = edgew(a0,b1,WS2), pDR1 = edgew(a1,b2,WS2);

    float psum = 0.0f;

    #pragma unroll
    for (int r = 0; r < 16; ++r) {
        // horizontal edges within row B
        float H0 = edgew(b0,b1,WS1), H1 = edgew(b1,b2,WS1), H2 = edgew(b2,b3,WS1);
        // B-K edges (used as C-row weights now; reused as A-row weights next iter)
        float V1  = edgew(b1,k1,WS1), V2  = edgew(b2,k2,WS1);
        float DL1 = edgew(b1,k0,WS2), DL2 = edgew(b2,k1,WS2), DL3 = edgew(b3,k2,WS2);
        float DR0 = edgew(b0,k1,WS2), DR1 = edgew(b1,k2,WS2), DR2 = edgew(b2,k3,WS2);

#define PIXEL(am,ac,ap, bm,bc,bp, km,kc,kp, wAL,wAC,wAR, wBL,wBR, wCL,wCV,wCR) { \
        float num = bc; \
        num = fmaf(wAL, am, num); num = fmaf(wAC, ac, num); num = fmaf(wAR, ap, num); \
        num = fmaf(wBL, bm, num); num = fmaf(wBR, bp, num); \
        num = fmaf(wCL, km, num); num = fmaf(wCV, kc, num); num = fmaf(wCR, kp, num); \
        float den = 1.0f + (((wAL + wAC) + (wAR + wBL)) + ((wBR + wCL) + (wCV + wCR))); \
        psum = fmaf(num, __builtin_amdgcn_rcpf(den), psum); }

        // pixel at col c (center b1) and col c+1 (center b2)
        PIXEL(a0,a1,a2, b0,b1,b2, k0,k1,k2, pDR0,pV1,pDL2, H0,H1, DL1,V1,DR1)
        PIXEL(a1,a2,a3, b1,b2,b3, k1,k2,k3, pDR1,pV2,pDL3, H1,H2, DL2,V2,DR2)
#undef PIXEL

        // rotate rows
        a0=b0;a1=b1;a2=b2;a3=b3;
        b0=k0;b1=k1;b2=k2;b3=k3;
        k0=p0;k1=p1;k2=p2;k3=p3;
        // carried edges for next iteration
        pV1=V1; pV2=V2; pDL2=DL2; pDL3=DL3; pDR0=DR0; pDR1=DR1;
        if (r < 14) { LOADROW(r+3, p0,p1,p2,p3) }
    }
#undef LOADROW

    // pool block = 16 cols = 8 lanes (2 cols each); 16 rows already in psum
    psum += __shfl_xor(psum, 1);
    psum += __shfl_xor(psum, 2);
    psum += __shfl_xor(psum, 4);

    if ((t & 7) == 0) {
        const int pc = (ch << 5) + (t >> 3);   // pool col 0..63
        out[(size_t)((b << 6) + pr) * 64 + pc] = psum * (1.0f / 256.0f);
    }
}

extern "C" void kernel_launch(void* const* d_in, const int* in_sizes, int n_in,
                              void* d_out, int out_size, void* d_ws, size_t ws_size,
                              hipStream_t stream) {
    const float* x = (const float*)d_in[0];
    float* out     = (float*)d_out;
    // grid: 16 batches * 64 pool rows * 2 column halves; 256 threads (2 cols x 16 rows each)
    EdgePreserve_kernel<<<dim3(16 * 64 * 2), dim3(256), 0, stream>>>(x, out);
}

// Round 7
// 26.222 us; speedup vs baseline: 1.0762x; 1.0762x over previous
//
#include <hip/hip_runtime.h>

#define IMG_H 1024
#define IMG_W 1024

#define CC  (-0.1803368801111244f)     // -(1/8)*log2(e)
#define WS1 (-2.8853900817779270e-4f)  // log2(exp(-1/5000))
#define WS2 (-5.7707801635558540e-4f)  // log2(exp(-2/5000))

__device__ __forceinline__ float edgew(float u, float v, float ws) {
    float d = u - v;
    return __builtin_amdgcn_exp2f(fmaf(d * d, CC, ws));
}

__global__ __launch_bounds__(256) void EdgePreserve_kernel(const float* __restrict__ x,
                                                           float* __restrict__ out) {
    const int t   = threadIdx.x;
    const int bid = blockIdx.x;         // b*64 + pool_row
    const int b   = bid >> 6;
    const int pr  = bid & 63;
    const int r0  = pr << 4;
    const int c0  = t << 2;             // 4 cols per thread; block covers full 1024-col row

    const float* base = x + (size_t)b * (IMG_H * IMG_W);
    const int cl = (c0 == 0) ? 1 : c0 - 1;                 // reflect left halo col
    const int cr = (c0 + 4 >= IMG_W) ? IMG_W - 2 : c0 + 4; // reflect right halo col

    // rows as named scalars: a=r-1, b=r, k=r+1, p=prefetch(r+3); cols {halo, c..c+3, halo}
    float a0,a1,a2,a3,a4,a5, b0,b1,b2,b3,b4,b5, k0,k1,k2,k3,k4,k5, p0,p1,p2,p3,p4,p5;

#define LOADROW(q, d0,d1,d2,d3,d4,d5) { \
    int _r = r0 + (q); \
    int _rr = (_r < 0) ? -_r : ((_r >= IMG_H) ? (2*IMG_H-2-_r) : _r); \
    const float* _rp = base + _rr * IMG_W; \
    float4 _v = *reinterpret_cast<const float4*>(_rp + c0); \
    d0 = _rp[cl]; d1 = _v.x; d2 = _v.y; d3 = _v.z; d4 = _v.w; d5 = _rp[cr]; }

    LOADROW(-1, a0,a1,a2,a3,a4,a5)
    LOADROW( 0, b0,b1,b2,b3,b4,b5)
    LOADROW( 1, k0,k1,k2,k3,k4,k5)
    LOADROW( 2, p0,p1,p2,p3,p4,p5)

    // carried A-B edge weights:
    // pV_c = w(a_c,b_c); pDL_c = w(a_c,b_{c-1}); pDR_c = w(a_c,b_{c+1})
    float pV1 = edgew(a1,b1,WS1), pV2 = edgew(a2,b2,WS1), pV3 = edgew(a3,b3,WS1), pV4 = edgew(a4,b4,WS1);
    float pDL2 = edgew(a2,b1,WS2), pDL3 = edgew(a3,b2,WS2), pDL4 = edgew(a4,b3,WS2), pDL5 = edgew(a5,b4,WS2);
    float pDR0 = edgew(a0,b1,WS2), pDR1 = edgew(a1,b2,WS2), pDR2 = edgew(a2,b3,WS2), pDR3 = edgew(a3,b4,WS2);

    float psum = 0.0f;

    #pragma unroll
    for (int r = 0; r < 16; ++r) {
        // horizontal edges within row B (shared by adjacent pixels)
        float H0 = edgew(b0,b1,WS1), H1 = edgew(b1,b2,WS1), H2 = edgew(b2,b3,WS1),
              H3 = edgew(b3,b4,WS1), H4 = edgew(b4,b5,WS1);
        // B-K edges (C-row weights now; A-row weights next iteration)
        float V1  = edgew(b1,k1,WS1), V2  = edgew(b2,k2,WS1), V3  = edgew(b3,k3,WS1), V4 = edgew(b4,k4,WS1);
        float DL1 = edgew(b1,k0,WS2), DL2 = edgew(b2,k1,WS2), DL3 = edgew(b3,k2,WS2),
              DL4 = edgew(b4,k3,WS2), DL5 = edgew(b5,k4,WS2);
        float DR0 = edgew(b0,k1,WS2), DR1 = edgew(b1,k2,WS2), DR2 = edgew(b2,k3,WS2),
              DR3 = edgew(b3,k4,WS2), DR4 = edgew(b4,k5,WS2);

#define PIXEL(am,ac,ap, bm,bc,bp, km,kc,kp, wAL,wAC,wAR, wBL,wBR, wCL,wCV,wCR) { \
        float num = bc; \
        num = fmaf(wAL, am, num); num = fmaf(wAC, ac, num); num = fmaf(wAR, ap, num); \
        num = fmaf(wBL, bm, num); num = fmaf(wBR, bp, num); \
        num = fmaf(wCL, km, num); num = fmaf(wCV, kc, num); num = fmaf(wCR, kp, num); \
        float den = 1.0f + (((wAL + wAC) + (wAR + wBL)) + ((wBR + wCL) + (wCV + wCR))); \
        psum = fmaf(num, __builtin_amdgcn_rcpf(den), psum); }

        PIXEL(a0,a1,a2, b0,b1,b2, k0,k1,k2, pDR0,pV1,pDL2, H0,H1, DL1,V1,DR1)
        PIXEL(a1,a2,a3, b1,b2,b3, k1,k2,k3, pDR1,pV2,pDL3, H1,H2, DL2,V2,DR2)
        PIXEL(a2,a3,a4, b2,b3,b4, k2,k3,k4, pDR2,pV3,pDL4, H2,H3, DL3,V3,DR3)
        PIXEL(a3,a4,a5, b3,b4,b5, k3,k4,k5, pDR3,pV4,pDL5, H3,H4, DL4,V4,DR4)
#undef PIXEL

        // rotate rows
        a0=b0;a1=b1;a2=b2;a3=b3;a4=b4;a5=b5;
        b0=k0;b1=k1;b2=k2;b3=k3;b4=k4;b5=k5;
        k0=p0;k1=p1;k2=p2;k3=p3;k4=p4;k5=p5;
        // next iter's A-row weights = this iter's B-K edges
        pV1=V1;  pV2=V2;  pV3=V3;  pV4=V4;
        pDL2=DL2;pDL3=DL3;pDL4=DL4;pDL5=DL5;
        pDR0=DR0;pDR1=DR1;pDR2=DR2;pDR3=DR3;
        if (r < 14) { LOADROW(r+3, p0,p1,p2,p3,p4,p5) }
    }
#undef LOADROW

    // pool block = 16 cols = 4 lanes (4 cols each); 16 rows already accumulated
    psum += __shfl_xor(psum, 1);
    psum += __shfl_xor(psum, 2);

    if ((t & 3) == 0) {
        out[(size_t)bid * 64 + (t >> 2)] = psum * (1.0f / 256.0f);
    }
}

extern "C" void kernel_launch(void* const* d_in, const int* in_sizes, int n_in,
                              void* d_out, int out_size, void* d_ws, size_t ws_size,
                              hipStream_t stream) {
    const float* x = (const float*)d_in[0];
    float* out     = (float*)d_out;
    // grid: 16 batches * 64 pool rows = 1024 blocks of 256 threads (4 cols x 16 rows each)
    // = 4 blocks/CU x 4 waves -> fully resident, no dispatch tail
    EdgePreserve_kernel<<<dim3(16 * 64), dim3(256), 0, stream>>>(x, out);
}